// Round 1
// 460.170 us; speedup vs baseline: 1.1322x; 1.1322x over previous
//
#include <hip/hip_runtime.h>
#include <stdint.h>

#define N_NODES 50000
#define N_EDGES 800000
#define IN_CH   512
#define HID_CH  256
#define OUT_CH  128
#define NPAD    50048
#define SLOT    96      // padded CSR slots/node; P(Poisson(16) > 96) ~ 0

#define NB_E   3125     // ceil(800000/256)
#define NB2    391      // 128-row GEMM tiles = partial max blocks

// k_prep block ranges (each block covers 2048 elements)
#define PZ    25        // cnt zero: 25*2048 >= 50000
#define PW0B  (PZ + 64)   // W0 split+T: 131072/2048
#define PW1B  (PW0B + 16) // W1 split+T: 32768/2048
#define PPWB  (PW1B + 8)  // PW split+T: 16384/2048

typedef unsigned short ushort_t;
typedef __attribute__((ext_vector_type(8))) short    short8;  // 8 bf16 (MFMA A/B frag)
typedef __attribute__((ext_vector_type(4))) float    floatx4; // MFMA C/D frag
typedef __attribute__((ext_vector_type(4))) _Float16 half4v;  // 8B gather chunk
typedef __attribute__((ext_vector_type(2))) _Float16 half2v;  // 4B gather chunk

__device__ inline ushort_t f2bf(float x) {                  // fp32 -> bf16 RNE
    union { float f; unsigned u; } v; v.f = x;
    unsigned r = v.u + 0x7fffu + ((v.u >> 16) & 1u);
    return (ushort_t)(r >> 16);
}
__device__ inline float bf2f(ushort_t h) {
    union { unsigned u; float f; } v; v.u = ((unsigned)h) << 16;
    return v.f;
}
__device__ inline void gl_lds16(const void* g, void* l) {   // async global->LDS, 16B/lane
    __builtin_amdgcn_global_load_lds((const __attribute__((address_space(1))) void*)g,
                                     (__attribute__((address_space(3))) void*)l, 16, 0, 0);
}

// LDS bank swizzle: XOR on the element index that moves the 16B chunk of a
// 64B row by (row>>1)&3 chunks.  Makes each 16-lane phase of ds_read_b128 hit
// all 8 bank quads (2-way = free) instead of 2 quads (8-way).
// Every producer of split-bf16 GEMM operands stores through the SAME swizzle,
// so global_load_lds (linear dest) lands already-swizzled tiles in LDS.
#define SWZ(r) ((((r) >> 1) & 3) << 3)

// ---------------- fused prep: cnt zero + weight split+transpose (swizzled) --------------
__device__ inline void conv_splitT8(const float* __restrict__ W,
                                    ushort_t* __restrict__ WhT,
                                    ushort_t* __restrict__ WlT,
                                    int K, int N, int base) {
    float4 v0 = *(const float4*)(W + base);
    float4 v1 = *(const float4*)(W + base + 4);
    float vv[8] = {v0.x, v0.y, v0.z, v0.w, v1.x, v1.y, v1.z, v1.w};
    #pragma unroll
    for (int j = 0; j < 8; ++j) {
        int g = base + j;
        int k = g / N, n = g - k * N;
        int ks = k ^ SWZ(n);                       // swizzled storage position
        ushort_t h = f2bf(vv[j]);
        WhT[(size_t)n * K + ks] = h;
        WlT[(size_t)n * K + ks] = f2bf(vv[j] - bf2f(h));
    }
}

__global__ __launch_bounds__(256) void k_prep(const float* __restrict__ W0,
                                              const float* __restrict__ W1,
                                              const float* __restrict__ PW,
                                              int* __restrict__ cnt,
                                              ushort_t* W0hT, ushort_t* W0lT,
                                              ushort_t* W1hT, ushort_t* W1lT,
                                              ushort_t* PWhT, ushort_t* PWlT) {
    int b = blockIdx.x, tid = threadIdx.x;
    if (b < PZ) {                                  // zero cnt
        int base = b * 2048 + tid * 8;
        #pragma unroll
        for (int j = 0; j < 8; ++j)
            if (base + j < N_NODES) cnt[base + j] = 0;
    } else if (b < PW0B) {
        conv_splitT8(W0, W0hT, W0lT, IN_CH, HID_CH, (b - PZ) * 2048 + tid * 8);
    } else if (b < PW1B) {
        conv_splitT8(W1, W1hT, W1lT, HID_CH, OUT_CH, (b - PW0B) * 2048 + tid * 8);
    } else {
        conv_splitT8(PW, PWhT, PWlT, OUT_CH, OUT_CH, (b - PW1B) * 2048 + tid * 8);
    }
}

// ---------------- padded-bucket CSR (no scan) ----------------
__global__ __launch_bounds__(256) void k_bucket(const int* __restrict__ esrc,
                                                const int* __restrict__ edst,
                                                int* __restrict__ cnt,
                                                int* __restrict__ slots) {
    int e = blockIdx.x * 256 + threadIdx.x;
    if (e < N_EDGES) {
        int d = edst[e];
        int c = atomicAdd(&cnt[d], 1);
        slots[(size_t)d * SLOT + c] = esrc[e];
    }
}

__global__ __launch_bounds__(256) void k_dinv(const int* __restrict__ cnt,
                                              float* __restrict__ dinv) {
    int i = blockIdx.x * 256 + threadIdx.x;
    if (i < N_NODES) dinv[i] = rsqrtf((float)cnt[i] + 1.0f);   // +1 self loop
}

// =====================================================================
// GEMM0: C[M,N] = x[M,K] @ B[K,N], A read as RAW FP32 and split in-registers
// (kills the separate x-split prep pass; identical numerics).
// 128x128 tile, BK=32, 4 waves, wave 64x64 (4x4 16x16 tiles), 3-MFMA split.
// A: reg-staged with swizzled ds_write; B: global_load_lds from pre-swizzled
// weight storage.  All frag reads use the SWZ chunk XOR (bank-conflict-free).
// =====================================================================
__global__ __launch_bounds__(256) void gemm0_x(const float* __restrict__ A,
                                               const ushort_t* __restrict__ BhT,
                                               const ushort_t* __restrict__ BlT,
                                               _Float16* __restrict__ C,
                                               int M, int N, int K) {
    __shared__ ushort_t sm[4][128 * 32];           // 0=Ah 1=Al 2=Bh 3=Bl
    const int tid  = threadIdx.x;
    const int wave = tid >> 6, lane = tid & 63;
    const int m0 = blockIdx.y * 128, n0 = blockIdx.x * 128;

    // --- A staging map: thread -> (row sr, 16-float segment sseg) ---
    const int sr = tid >> 1, sseg = tid & 1;
    const float* gA = A + (size_t)min(m0 + sr, M - 1) * K + sseg * 16;
    const int swa = (sr >> 1) & 3;
    ushort_t* wh0 = &sm[0][sr * 32 + (((sseg * 2)     ^ swa) * 8)];
    ushort_t* wh1 = &sm[0][sr * 32 + (((sseg * 2 + 1) ^ swa) * 8)];
    ushort_t* wl0 = &sm[1][sr * 32 + (((sseg * 2)     ^ swa) * 8)];
    ushort_t* wl1 = &sm[1][sr * 32 + (((sseg * 2 + 1) ^ swa) * 8)];

    // --- B staging via global_load_lds (storage pre-swizzled in k_prep) ---
    const int c0 = wave * 128 + lane, c1 = c0 + 64;
    const ushort_t* gbh0 = BhT + (size_t)(n0 + (c0 >> 2)) * K + (c0 & 3) * 8;
    const ushort_t* gbh1 = BhT + (size_t)(n0 + (c1 >> 2)) * K + (c1 & 3) * 8;
    const ushort_t* gbl0 = BlT + (size_t)(n0 + (c0 >> 2)) * K + (c0 & 3) * 8;
    const ushort_t* gbl1 = BlT + (size_t)(n0 + (c1 >> 2)) * K + (c1 & 3) * 8;
    ushort_t* lb0 = &sm[2][wave * 1024];  ushort_t* lb1 = &sm[2][wave * 1024 + 512];
    ushort_t* lc0 = &sm[3][wave * 1024];  ushort_t* lc1 = &sm[3][wave * 1024 + 512];

    floatx4 zero = {0.f, 0.f, 0.f, 0.f};
    floatx4 acc[4][4];
    #pragma unroll
    for (int i = 0; i < 4; ++i)
        #pragma unroll
        for (int j = 0; j < 4; ++j) acc[i][j] = zero;

    const int wm = (wave & 1) * 64, wn = (wave >> 1) * 64;
    const int fr = lane & 15, fq = lane >> 4;
    const int sx = SWZ(fr);                        // row bits 1-2 only -> per-lane const

    for (int k0 = 0; k0 < K; k0 += 32) {
        gl_lds16(gbh0, lb0); gl_lds16(gbh1, lb1);
        gl_lds16(gbl0, lc0); gl_lds16(gbl1, lc1);
        gbh0 += 32; gbh1 += 32; gbl0 += 32; gbl1 += 32;
        float4 q0 = ((const float4*)gA)[0];
        float4 q1 = ((const float4*)gA)[1];
        float4 q2 = ((const float4*)gA)[2];
        float4 q3 = ((const float4*)gA)[3];
        gA += 32;
        float vv[16] = {q0.x, q0.y, q0.z, q0.w, q1.x, q1.y, q1.z, q1.w,
                        q2.x, q2.y, q2.z, q2.w, q3.x, q3.y, q3.z, q3.w};
        union { ushort_t u[8]; short8 v; } h0u, h1u, l0u, l1u;
        #pragma unroll
        for (int j = 0; j < 8; ++j) {
            ushort_t h = f2bf(vv[j]);
            h0u.u[j] = h; l0u.u[j] = f2bf(vv[j] - bf2f(h));
        }
        #pragma unroll
        for (int j = 0; j < 8; ++j) {
            ushort_t h = f2bf(vv[8 + j]);
            h1u.u[j] = h; l1u.u[j] = f2bf(vv[8 + j] - bf2f(h));
        }
        *(short8*)wh0 = h0u.v; *(short8*)wh1 = h1u.v;
        *(short8*)wl0 = l0u.v; *(short8*)wl1 = l1u.v;
        __syncthreads();
        short8 afh[4], afl[4], bfh[4], bfl[4];
        #pragma unroll
        for (int t = 0; t < 4; ++t) {
            int ai = (wm + t * 16 + fr) * 32 + (fq * 8 ^ sx);
            int bi = (wn + t * 16 + fr) * 32 + (fq * 8 ^ sx);
            afh[t] = *(const short8*)&sm[0][ai];
            afl[t] = *(const short8*)&sm[1][ai];
            bfh[t] = *(const short8*)&sm[2][bi];
            bfl[t] = *(const short8*)&sm[3][bi];
        }
        #pragma unroll
        for (int i = 0; i < 4; ++i)
            #pragma unroll
            for (int j = 0; j < 4; ++j) {
                acc[i][j] = __builtin_amdgcn_mfma_f32_16x16x32_bf16(afh[i], bfh[j], acc[i][j], 0, 0, 0);
                acc[i][j] = __builtin_amdgcn_mfma_f32_16x16x32_bf16(afh[i], bfl[j], acc[i][j], 0, 0, 0);
                acc[i][j] = __builtin_amdgcn_mfma_f32_16x16x32_bf16(afl[i], bfh[j], acc[i][j], 0, 0, 0);
            }
        __syncthreads();
    }
    const int colb = n0 + wn + fr;
    #pragma unroll
    for (int i = 0; i < 4; ++i) {
        int rowb = m0 + wm + i * 16 + fq * 4;
        #pragma unroll
        for (int r = 0; r < 4; ++r) {
            int row = rowb + r;
            if (row < M) {
                _Float16* cp = C + (size_t)row * N + colb;
                cp[0]  = (_Float16)acc[i][0][r];
                cp[16] = (_Float16)acc[i][1][r];
                cp[32] = (_Float16)acc[i][2][r];
                cp[48] = (_Float16)acc[i][3][r];
            }
        }
    }
}

// =====================================================================
// GEMM1: split-bf16 A/B from pre-swizzled storage (agg/prep outputs)
// =====================================================================
__global__ __launch_bounds__(256) void gemm_bf(const ushort_t* __restrict__ Ah,
                                               const ushort_t* __restrict__ Al,
                                               const ushort_t* __restrict__ BhT,
                                               const ushort_t* __restrict__ BlT,
                                               _Float16* __restrict__ C,
                                               int M, int N, int K) {
    __shared__ ushort_t sm[4][128 * 32];
    const int tid  = threadIdx.x;
    const int wave = tid >> 6, lane = tid & 63;
    const int m0 = blockIdx.y * 128, n0 = blockIdx.x * 128;

    const int c0 = wave * 128 + lane, c1 = c0 + 64;
    const int ar0 = min(m0 + (c0 >> 2), M - 1), ar1 = min(m0 + (c1 >> 2), M - 1);
    const ushort_t* gah0 = Ah + (size_t)ar0 * K + (c0 & 3) * 8;
    const ushort_t* gah1 = Ah + (size_t)ar1 * K + (c1 & 3) * 8;
    const ushort_t* gal0 = Al + (size_t)ar0 * K + (c0 & 3) * 8;
    const ushort_t* gal1 = Al + (size_t)ar1 * K + (c1 & 3) * 8;
    const ushort_t* gbh0 = BhT + (size_t)(n0 + (c0 >> 2)) * K + (c0 & 3) * 8;
    const ushort_t* gbh1 = BhT + (size_t)(n0 + (c1 >> 2)) * K + (c1 & 3) * 8;
    const ushort_t* gbl0 = BlT + (size_t)(n0 + (c0 >> 2)) * K + (c0 & 3) * 8;
    const ushort_t* gbl1 = BlT + (size_t)(n0 + (c1 >> 2)) * K + (c1 & 3) * 8;
    ushort_t* la0 = &sm[0][wave * 1024];       ushort_t* la1 = &sm[0][wave * 1024 + 512];
    ushort_t* ll0 = &sm[1][wave * 1024];       ushort_t* ll1 = &sm[1][wave * 1024 + 512];
    ushort_t* lb0 = &sm[2][wave * 1024];       ushort_t* lb1 = &sm[2][wave * 1024 + 512];
    ushort_t* lc0 = &sm[3][wave * 1024];       ushort_t* lc1 = &sm[3][wave * 1024 + 512];

    floatx4 zero = {0.f, 0.f, 0.f, 0.f};
    floatx4 acc[4][4];
    #pragma unroll
    for (int i = 0; i < 4; ++i)
        #pragma unroll
        for (int j = 0; j < 4; ++j) acc[i][j] = zero;

    const int wm = (wave & 1) * 64, wn = (wave >> 1) * 64;
    const int fr = lane & 15, fq = lane >> 4;
    const int sx = SWZ(fr);

    for (int k0 = 0; k0 < K; k0 += 32) {
        gl_lds16(gah0, la0); gl_lds16(gah1, la1);
        gl_lds16(gal0, ll0); gl_lds16(gal1, ll1);
        gl_lds16(gbh0, lb0); gl_lds16(gbh1, lb1);
        gl_lds16(gbl0, lc0); gl_lds16(gbl1, lc1);
        gah0 += 32; gah1 += 32; gal0 += 32; gal1 += 32;
        gbh0 += 32; gbh1 += 32; gbl0 += 32; gbl1 += 32;
        __syncthreads();
        short8 afh[4], afl[4], bfh[4], bfl[4];
        #pragma unroll
        for (int t = 0; t < 4; ++t) {
            int ai = (wm + t * 16 + fr) * 32 + (fq * 8 ^ sx);
            int bi = (wn + t * 16 + fr) * 32 + (fq * 8 ^ sx);
            afh[t] = *(const short8*)&sm[0][ai];
            afl[t] = *(const short8*)&sm[1][ai];
            bfh[t] = *(const short8*)&sm[2][bi];
            bfl[t] = *(const short8*)&sm[3][bi];
        }
        #pragma unroll
        for (int i = 0; i < 4; ++i)
            #pragma unroll
            for (int j = 0; j < 4; ++j) {
                acc[i][j] = __builtin_amdgcn_mfma_f32_16x16x32_bf16(afh[i], bfh[j], acc[i][j], 0, 0, 0);
                acc[i][j] = __builtin_amdgcn_mfma_f32_16x16x32_bf16(afh[i], bfl[j], acc[i][j], 0, 0, 0);
                acc[i][j] = __builtin_amdgcn_mfma_f32_16x16x32_bf16(afl[i], bfh[j], acc[i][j], 0, 0, 0);
            }
        __syncthreads();
    }
    const int colb = n0 + wn + fr;
    #pragma unroll
    for (int i = 0; i < 4; ++i) {
        int rowb = m0 + wm + i * 16 + fq * 4;
        #pragma unroll
        for (int r = 0; r < 4; ++r) {
            int row = rowb + r;
            if (row < M) {
                _Float16* cp = C + (size_t)row * N + colb;
                cp[0]  = (_Float16)acc[i][0][r];
                cp[16] = (_Float16)acc[i][1][r];
                cp[32] = (_Float16)acc[i][2][r];
                cp[48] = (_Float16)acc[i][3][r];
            }
        }
    }
}

// =====================================================================
// PGE GEMM: p-tile = h1 @ PW with FUSED per-block column max/argmax.
// p is never materialized (saves 51MB HBM round trip + k_reduce1).
// grid: NB2 blocks of 128 rows; N fixed = 128 (n0 = 0).
// =====================================================================
__global__ __launch_bounds__(256) void gemm_pge(const ushort_t* __restrict__ Ah,
                                                const ushort_t* __restrict__ Al,
                                                const ushort_t* __restrict__ BhT,
                                                const ushort_t* __restrict__ BlT,
                                                float* __restrict__ pv,
                                                int* __restrict__ pi,
                                                int M, int K) {
    __shared__ ushort_t sm[4][128 * 32];
    __shared__ float redv[8][128];
    __shared__ int   redi[8][128];
    const int tid  = threadIdx.x;
    const int wave = tid >> 6, lane = tid & 63;
    const int m0 = blockIdx.x * 128;

    const int c0 = wave * 128 + lane, c1 = c0 + 64;
    const int ar0 = min(m0 + (c0 >> 2), M - 1), ar1 = min(m0 + (c1 >> 2), M - 1);
    const ushort_t* gah0 = Ah + (size_t)ar0 * K + (c0 & 3) * 8;
    const ushort_t* gah1 = Ah + (size_t)ar1 * K + (c1 & 3) * 8;
    const ushort_t* gal0 = Al + (size_t)ar0 * K + (c0 & 3) * 8;
    const ushort_t* gal1 = Al + (size_t)ar1 * K + (c1 & 3) * 8;
    const ushort_t* gbh0 = BhT + (size_t)(c0 >> 2) * K + (c0 & 3) * 8;
    const ushort_t* gbh1 = BhT + (size_t)(c1 >> 2) * K + (c1 & 3) * 8;
    const ushort_t* gbl0 = BlT + (size_t)(c0 >> 2) * K + (c0 & 3) * 8;
    const ushort_t* gbl1 = BlT + (size_t)(c1 >> 2) * K + (c1 & 3) * 8;
    ushort_t* la0 = &sm[0][wave * 1024];       ushort_t* la1 = &sm[0][wave * 1024 + 512];
    ushort_t* ll0 = &sm[1][wave * 1024];       ushort_t* ll1 = &sm[1][wave * 1024 + 512];
    ushort_t* lb0 = &sm[2][wave * 1024];       ushort_t* lb1 = &sm[2][wave * 1024 + 512];
    ushort_t* lc0 = &sm[3][wave * 1024];       ushort_t* lc1 = &sm[3][wave * 1024 + 512];

    floatx4 zero = {0.f, 0.f, 0.f, 0.f};
    floatx4 acc[4][4];
    #pragma unroll
    for (int i = 0; i < 4; ++i)
        #pragma unroll
        for (int j = 0; j < 4; ++j) acc[i][j] = zero;

    const int wm = (wave & 1) * 64, wn = (wave >> 1) * 64;
    const int fr = lane & 15, fq = lane >> 4;
    const int sx = SWZ(fr);

    for (int k0 = 0; k0 < K; k0 += 32) {
        gl_lds16(gah0, la0); gl_lds16(gah1, la1);
        gl_lds16(gal0, ll0); gl_lds16(gal1, ll1);
        gl_lds16(gbh0, lb0); gl_lds16(gbh1, lb1);
        gl_lds16(gbl0, lc0); gl_lds16(gbl1, lc1);
        gah0 += 32; gah1 += 32; gal0 += 32; gal1 += 32;
        gbh0 += 32; gbh1 += 32; gbl0 += 32; gbl1 += 32;
        __syncthreads();
        short8 afh[4], afl[4], bfh[4], bfl[4];
        #pragma unroll
        for (int t = 0; t < 4; ++t) {
            int ai = (wm + t * 16 + fr) * 32 + (fq * 8 ^ sx);
            int bi = (wn + t * 16 + fr) * 32 + (fq * 8 ^ sx);
            afh[t] = *(const short8*)&sm[0][ai];
            afl[t] = *(const short8*)&sm[1][ai];
            bfh[t] = *(const short8*)&sm[2][bi];
            bfl[t] = *(const short8*)&sm[3][bi];
        }
        #pragma unroll
        for (int i = 0; i < 4; ++i)
            #pragma unroll
            for (int j = 0; j < 4; ++j) {
                acc[i][j] = __builtin_amdgcn_mfma_f32_16x16x32_bf16(afh[i], bfh[j], acc[i][j], 0, 0, 0);
                acc[i][j] = __builtin_amdgcn_mfma_f32_16x16x32_bf16(afh[i], bfl[j], acc[i][j], 0, 0, 0);
                acc[i][j] = __builtin_amdgcn_mfma_f32_16x16x32_bf16(afl[i], bfh[j], acc[i][j], 0, 0, 0);
            }
        __syncthreads();
    }
    // ---- fused epilogue: column max/argmax over this 128-row strip ----
    const int slot = (wave & 1) * 4 + fq;          // (wm-half, fq) -> 8 slots per column
    #pragma unroll
    for (int j = 0; j < 4; ++j) {
        float bv = -3.402823466e+38f; int bidx = 0;
        #pragma unroll
        for (int i = 0; i < 4; ++i) {
            int rowb = m0 + wm + i * 16 + fq * 4;
            #pragma unroll
            for (int r = 0; r < 4; ++r) {
                int row = rowb + r;
                float v = acc[i][j][r];
                if (row < M && v > bv) { bv = v; bidx = row; }   // strict > keeps lowest row
            }
        }
        redv[slot][wn + j * 16 + fr] = bv;
        redi[slot][wn + j * 16 + fr] = bidx;
    }
    __syncthreads();
    if (tid < 128) {
        float bv = redv[0][tid]; int bidx = redi[0][tid];
        #pragma unroll
        for (int s = 1; s < 8; ++s) {
            float v = redv[s][tid]; int ix = redi[s][tid];
            if (v > bv || (v == bv && ix < bidx)) { bv = v; bidx = ix; }
        }
        pv[blockIdx.x * 128 + tid] = bv;
        pi[blockIdx.x * 128 + tid] = bidx;
    }
}

// ---------------- aggregation (bucket gather, fp16 table), 4 dst/block, 8-deep ----------
__global__ __launch_bounds__(256) void agg256_relu_bf(const _Float16* __restrict__ hl,
                                                      const float* __restrict__ dinv,
                                                      const int* __restrict__ cnt,
                                                      const int* __restrict__ slots,
                                                      const float* __restrict__ bias,
                                                      ushort_t* __restrict__ oh,
                                                      ushort_t* __restrict__ ol) {
    int d = blockIdx.x * 4 + (threadIdx.x >> 6);
    int lane = threadIdx.x & 63;
    float di = dinv[d];
    half4v v = ((const half4v*)(hl + (size_t)d * 256))[lane];
    float w = di * di;
    float ax = w * (float)v[0], ay = w * (float)v[1];
    float az = w * (float)v[2], aw = w * (float)v[3];
    const int* sl = slots + (size_t)d * SLOT;
    int n = cnt[d];
    int e = 0;
    for (; e + 8 <= n; e += 8) {
        int s[8]; half4v u[8]; float ws[8];
        #pragma unroll
        for (int j = 0; j < 8; ++j) s[j] = sl[e + j];
        #pragma unroll
        for (int j = 0; j < 8; ++j) u[j] = ((const half4v*)(hl + (size_t)s[j] * 256))[lane];
        #pragma unroll
        for (int j = 0; j < 8; ++j) ws[j] = dinv[s[j]] * di;
        #pragma unroll
        for (int j = 0; j < 8; ++j) {
            ax += ws[j] * (float)u[j][0]; ay += ws[j] * (float)u[j][1];
            az += ws[j] * (float)u[j][2]; aw += ws[j] * (float)u[j][3];
        }
    }
    for (; e < n; ++e) {
        int s = sl[e];
        float ws = dinv[s] * di;
        half4v u = ((const half4v*)(hl + (size_t)s * 256))[lane];
        ax += ws * (float)u[0]; ay += ws * (float)u[1];
        az += ws * (float)u[2]; aw += ws * (float)u[3];
    }
    float4 b = ((const float4*)bias)[lane];
    float rx = fmaxf(ax + b.x, 0.0f), ry = fmaxf(ay + b.y, 0.0f);
    float rz = fmaxf(az + b.z, 0.0f), rw = fmaxf(aw + b.w, 0.0f);
    ushort4 hv, lv;
    hv.x = f2bf(rx); lv.x = f2bf(rx - bf2f(hv.x));
    hv.y = f2bf(ry); lv.y = f2bf(ry - bf2f(hv.y));
    hv.z = f2bf(rz); lv.z = f2bf(rz - bf2f(hv.z));
    hv.w = f2bf(rw); lv.w = f2bf(rw - bf2f(hv.w));
    int sidx = (lane * 4) ^ SWZ(d);                // pre-swizzled split storage
    *(ushort4*)&oh[(size_t)d * 256 + sidx] = hv;
    *(ushort4*)&ol[(size_t)d * 256 + sidx] = lv;
}

__global__ __launch_bounds__(256) void agg128_bias_bf(const _Float16* __restrict__ hl,
                                                      const float* __restrict__ dinv,
                                                      const int* __restrict__ cnt,
                                                      const int* __restrict__ slots,
                                                      const float* __restrict__ bias,
                                                      float* __restrict__ out,
                                                      ushort_t* __restrict__ oh,
                                                      ushort_t* __restrict__ ol) {
    int d = blockIdx.x * 4 + (threadIdx.x >> 6);
    int lane = threadIdx.x & 63;
    float di = dinv[d];
    half2v v = ((const half2v*)(hl + (size_t)d * 128))[lane];
    float w = di * di;
    float ax = w * (float)v[0], ay = w * (float)v[1];
    const int* sl = slots + (size_t)d * SLOT;
    int n = cnt[d];
    int e = 0;
    for (; e + 8 <= n; e += 8) {
        int s[8]; half2v u[8]; float ws[8];
        #pragma unroll
        for (int j = 0; j < 8; ++j) s[j] = sl[e + j];
        #pragma unroll
        for (int j = 0; j < 8; ++j) u[j] = ((const half2v*)(hl + (size_t)s[j] * 128))[lane];
        #pragma unroll
        for (int j = 0; j < 8; ++j) ws[j] = dinv[s[j]] * di;
        #pragma unroll
        for (int j = 0; j < 8; ++j) { ax += ws[j] * (float)u[j][0]; ay += ws[j] * (float)u[j][1]; }
    }
    for (; e < n; ++e) {
        int s = sl[e];
        float ws = dinv[s] * di;
        half2v u = ((const half2v*)(hl + (size_t)s * 128))[lane];
        ax += ws * (float)u[0]; ay += ws * (float)u[1];
    }
    float2 b = ((const float2*)bias)[lane];
    float rx = ax + b.x, ry = ay + b.y;                    // no relu (last conv layer)
    ((float2*)(out + (size_t)d * 128))[lane] = make_float2(rx, ry);
    ushort2 hv, lv;
    hv.x = f2bf(rx); lv.x = f2bf(rx - bf2f(hv.x));
    hv.y = f2bf(ry); lv.y = f2bf(ry - bf2f(hv.y));
    int sidx = (lane * 2) ^ SWZ(d);                // pre-swizzled split storage
    *(ushort2*)&oh[(size_t)d * 128 + sidx] = hv;
    *(ushort2*)&ol[(size_t)d * 128 + sidx] = lv;
}

// ---------------- final reduce over NB2 per-block partials ----------------
__global__ __launch_bounds__(256) void k_reduce2(const float* __restrict__ pv,
                                                 const int* __restrict__ pi,
                                                 const float* __restrict__ Pb,
                                                 float* __restrict__ out) {
    int c = threadIdx.x & 127, sub = threadIdx.x >> 7;
    float best = -3.402823466e+38f;
    int bi = 0;
    for (int b = sub; b < NB2; b += 2) {
        float v = pv[b * 128 + c];
        int ix = pi[b * 128 + c];
        if (v > best || (v == best && ix < bi)) { best = v; bi = ix; }
    }
    __shared__ float sv[128];
    __shared__ int   si[128];
    if (sub == 1) { sv[c] = best; si[c] = bi; }
    __syncthreads();
    if (sub == 0) {
        float v1 = sv[c]; int i1 = si[c];
        if (v1 > best || (v1 == best && i1 < bi)) { best = v1; bi = i1; }
        out[(size_t)N_NODES * OUT_CH + c]       = best + Pb[c];
        out[(size_t)N_NODES * OUT_CH + 128 + c] = (float)bi;
    }
}

extern "C" void kernel_launch(void* const* d_in, const int* in_sizes, int n_in,
                              void* d_out, int out_size, void* d_ws, size_t ws_size,
                              hipStream_t stream) {
    const float* x  = (const float*)d_in[0];
    const int*   ei = (const int*)d_in[1];
    const float* W0 = (const float*)d_in[2];
    const float* b0 = (const float*)d_in[3];
    const float* W1 = (const float*)d_in[4];
    const float* b1 = (const float*)d_in[5];
    const float* PW = (const float*)d_in[6];
    const float* Pb = (const float*)d_in[7];
    float* out = (float*)d_out;
    const int* esrc = ei;
    const int* edst = ei + N_EDGES;

    char* w = (char*)d_ws;
    size_t off = 0;
    auto alloc = [&](size_t bytes) -> void* {
        void* p = (void*)(w + off);
        off = (off + bytes + 255) & ~(size_t)255;
        return p;
    };
    int*       cnt    = (int*)alloc((size_t)N_NODES * 4);
    float*     dinv   = (float*)alloc((size_t)N_NODES * 4);
    int*       slots  = (int*)alloc((size_t)N_NODES * SLOT * 4);
    float*     pmax_v = (float*)alloc((size_t)NB2 * 128 * 4);
    int*       pmax_i = (int*)alloc((size_t)NB2 * 128 * 4);
    _Float16*  bufH   = (_Float16*)alloc((size_t)NPAD * 256 * 2);        // fp16 gather table
    ushort_t*  h0h    = (ushort_t*)alloc((size_t)N_NODES * HID_CH * 2);  // swizzled split
    ushort_t*  h0l    = (ushort_t*)alloc((size_t)N_NODES * HID_CH * 2);
    ushort_t*  h1h    = (ushort_t*)alloc((size_t)N_NODES * OUT_CH * 2);
    ushort_t*  h1l    = (ushort_t*)alloc((size_t)N_NODES * OUT_CH * 2);
    ushort_t*  W0hT   = (ushort_t*)alloc((size_t)IN_CH * HID_CH * 2);
    ushort_t*  W0lT   = (ushort_t*)alloc((size_t)IN_CH * HID_CH * 2);
    ushort_t*  W1hT   = (ushort_t*)alloc((size_t)HID_CH * OUT_CH * 2);
    ushort_t*  W1lT   = (ushort_t*)alloc((size_t)HID_CH * OUT_CH * 2);
    ushort_t*  PWhT   = (ushort_t*)alloc((size_t)OUT_CH * OUT_CH * 2);
    ushort_t*  PWlT   = (ushort_t*)alloc((size_t)OUT_CH * OUT_CH * 2);

    // --- prep: cnt zero + weight split/transpose (swizzled); x is NOT touched ---
    k_prep<<<PPWB, 256, 0, stream>>>(W0, W1, PW, cnt,
                                     W0hT, W0lT, W1hT, W1lT, PWhT, PWlT);
    // --- padded-bucket CSR + dinv ---
    k_bucket<<<NB_E, 256, 0, stream>>>(esrc, edst, cnt, slots);
    k_dinv<<<196, 256, 0, stream>>>(cnt, dinv);

    // --- layer 0: hl0 = x @ W0 (fp32 A split in-kernel) ; h0 = relu(agg+b0) ---
    gemm0_x<<<dim3(HID_CH / 128, NB2), 256, 0, stream>>>(
        x, W0hT, W0lT, bufH, N_NODES, HID_CH, IN_CH);
    agg256_relu_bf<<<N_NODES / 4, 256, 0, stream>>>(bufH, dinv, cnt, slots, b0, h0h, h0l);

    // --- layer 1: hl1 = h0 @ W1 ; h1 = agg(hl1) + b1 -> d_out + split bf16 ---
    gemm_bf<<<dim3(1, NB2), 256, 0, stream>>>(
        h0h, h0l, W1hT, W1lT, bufH, N_NODES, OUT_CH, HID_CH);
    agg128_bias_bf<<<N_NODES / 4, 256, 0, stream>>>(bufH, dinv, cnt, slots, b1,
                                                    out, h1h, h1l);

    // --- PGE: fused p = h1 @ PW with per-block max/argmax; final reduce ---
    gemm_pge<<<NB2, 256, 0, stream>>>(h1h, h1l, PWhT, PWlT, pmax_v, pmax_i,
                                      N_NODES, OUT_CH);
    k_reduce2<<<1, 256, 0, stream>>>(pmax_v, pmax_i, Pb, out);

    (void)in_sizes; (void)n_in; (void)out_size; (void)ws_size;
}

// Round 2
// 446.641 us; speedup vs baseline: 1.1665x; 1.0303x over previous
//
#include <hip/hip_runtime.h>
#include <stdint.h>

#define N_NODES 50000
#define N_EDGES 800000
#define IN_CH   512
#define HID_CH  256
#define OUT_CH  128
#define NPAD    50048
#define SLOT    96      // padded CSR slots/node; P(Poisson(16) > 96) ~ 0

#define NB_E   3125     // ceil(800000/256)
#define NB2    391      // 128-row GEMM tiles = partial max blocks

// k_prep block ranges (each block covers 2048 elements)
#define PZ    25        // cnt zero: 25*2048 >= 50000
#define PW0B  (PZ + 64)   // W0 split+T: 131072/2048
#define PW1B  (PW0B + 16) // W1 split+T: 32768/2048
#define PPWB  (PW1B + 8)  // PW split+T: 16384/2048

typedef unsigned short ushort_t;
typedef __attribute__((ext_vector_type(8))) short    short8;  // 8 bf16 (MFMA A/B frag)
typedef __attribute__((ext_vector_type(4))) float    floatx4; // MFMA C/D frag
typedef __attribute__((ext_vector_type(4))) _Float16 half4v;  // 8B gather chunk
typedef __attribute__((ext_vector_type(2))) _Float16 half2v;  // 4B gather chunk

__device__ inline ushort_t f2bf(float x) {                  // fp32 -> bf16 RNE
    union { float f; unsigned u; } v; v.f = x;
    unsigned r = v.u + 0x7fffu + ((v.u >> 16) & 1u);
    return (ushort_t)(r >> 16);
}
__device__ inline float bf2f(ushort_t h) {
    union { unsigned u; float f; } v; v.u = ((unsigned)h) << 16;
    return v.f;
}
__device__ inline void gl_lds16(const void* g, void* l) {   // async global->LDS, 16B/lane
    __builtin_amdgcn_global_load_lds((const __attribute__((address_space(1))) void*)g,
                                     (__attribute__((address_space(3))) void*)l, 16, 0, 0);
}

// LDS bank swizzle: XOR on the 16B-chunk index within each 64B k-row by
// (row>>1)&3.  All producers of split-bf16 GEMM operands store through the
// SAME swizzle so global_load_lds (linear dest) lands already-swizzled tiles.
#define SWZ(r) ((((r) >> 1) & 3) << 3)

// pipeline sync: counted vmcnt (never full-drain in steady state) + raw barrier
#define SYNC_PIPE(N) do {                                                    \
    asm volatile("s_waitcnt vmcnt(" #N ") lgkmcnt(0)" ::: "memory");         \
    __builtin_amdgcn_sched_barrier(0);                                       \
    __builtin_amdgcn_s_barrier();                                            \
    __builtin_amdgcn_sched_barrier(0); } while (0)

// ---------------- fused prep: cnt zero + weight split+transpose (swizzled) --------------
__device__ inline void conv_splitT8(const float* __restrict__ W,
                                    ushort_t* __restrict__ WhT,
                                    ushort_t* __restrict__ WlT,
                                    int K, int N, int base) {
    float4 v0 = *(const float4*)(W + base);
    float4 v1 = *(const float4*)(W + base + 4);
    float vv[8] = {v0.x, v0.y, v0.z, v0.w, v1.x, v1.y, v1.z, v1.w};
    #pragma unroll
    for (int j = 0; j < 8; ++j) {
        int g = base + j;
        int k = g / N, n = g - k * N;
        int ks = k ^ SWZ(n);                       // swizzled storage position
        ushort_t h = f2bf(vv[j]);
        WhT[(size_t)n * K + ks] = h;
        WlT[(size_t)n * K + ks] = f2bf(vv[j] - bf2f(h));
    }
}

__global__ __launch_bounds__(256) void k_prep(const float* __restrict__ W0,
                                              const float* __restrict__ W1,
                                              const float* __restrict__ PW,
                                              int* __restrict__ cnt,
                                              ushort_t* W0hT, ushort_t* W0lT,
                                              ushort_t* W1hT, ushort_t* W1lT,
                                              ushort_t* PWhT, ushort_t* PWlT) {
    int b = blockIdx.x, tid = threadIdx.x;
    if (b < PZ) {                                  // zero cnt
        int base = b * 2048 + tid * 8;
        #pragma unroll
        for (int j = 0; j < 8; ++j)
            if (base + j < N_NODES) cnt[base + j] = 0;
    } else if (b < PW0B) {
        conv_splitT8(W0, W0hT, W0lT, IN_CH, HID_CH, (b - PZ) * 2048 + tid * 8);
    } else if (b < PW1B) {
        conv_splitT8(W1, W1hT, W1lT, HID_CH, OUT_CH, (b - PW0B) * 2048 + tid * 8);
    } else {
        conv_splitT8(PW, PWhT, PWlT, OUT_CH, OUT_CH, (b - PW1B) * 2048 + tid * 8);
    }
}

// ---------------- padded-bucket CSR (no scan) ----------------
__global__ __launch_bounds__(256) void k_bucket(const int* __restrict__ esrc,
                                                const int* __restrict__ edst,
                                                int* __restrict__ cnt,
                                                int* __restrict__ slots) {
    int e = blockIdx.x * 256 + threadIdx.x;
    if (e < N_EDGES) {
        int d = edst[e];
        int c = atomicAdd(&cnt[d], 1);
        slots[(size_t)d * SLOT + c] = esrc[e];
    }
}

__global__ __launch_bounds__(256) void k_dinv(const int* __restrict__ cnt,
                                              float* __restrict__ dinv) {
    int i = blockIdx.x * 256 + threadIdx.x;
    if (i < N_NODES) dinv[i] = rsqrtf((float)cnt[i] + 1.0f);   // +1 self loop
}

// =====================================================================
// GEMM0: C = x @ W0, A read as RAW FP32, split in-registers, DOUBLE-BUFFERED
// pipeline with raw s_barrier + counted vmcnt.  A-regs prefetched one
// K-step ahead across the barrier (T14); B staged via global_load_lds from
// pre-swizzled storage.  Epilogue pre-scales rows by dinv[row] (for agg).
// =====================================================================
__global__ __launch_bounds__(256, 2) void gemm0_x(const float* __restrict__ A,
                                                  const ushort_t* __restrict__ BhT,
                                                  const ushort_t* __restrict__ BlT,
                                                  const float* __restrict__ dinv,
                                                  _Float16* __restrict__ C,
                                                  int M, int N) {
    constexpr int KT = IN_CH;
    constexpr int NT = KT / 32;                    // 16
    __shared__ ushort_t sm[2][4][128 * 32];        // [buf][Ah,Al,Bh,Bl]
    const int tid  = threadIdx.x;
    const int wave = tid >> 6, lane = tid & 63;
    const int m0 = blockIdx.y * 128, n0 = blockIdx.x * 128;

    // --- A staging map: thread -> (row sr, 16-float segment sseg) ---
    const int sr = tid >> 1, sseg = tid & 1;
    const float* gA = A + (size_t)min(m0 + sr, M - 1) * KT + sseg * 16;
    const int swa = (sr >> 1) & 3;
    const int wo0 = sr * 32 + (((sseg * 2)     ^ swa) * 8);
    const int wo1 = sr * 32 + (((sseg * 2 + 1) ^ swa) * 8);

    // --- B staging via global_load_lds (storage pre-swizzled in k_prep) ---
    const int c0 = wave * 128 + lane, c1 = c0 + 64;
    const ushort_t* gbh0 = BhT + (size_t)(n0 + (c0 >> 2)) * KT + (c0 & 3) * 8;
    const ushort_t* gbh1 = BhT + (size_t)(n0 + (c1 >> 2)) * KT + (c1 & 3) * 8;
    const ushort_t* gbl0 = BlT + (size_t)(n0 + (c0 >> 2)) * KT + (c0 & 3) * 8;
    const ushort_t* gbl1 = BlT + (size_t)(n0 + (c1 >> 2)) * KT + (c1 & 3) * 8;
    const int lo0 = wave * 1024, lo1 = wave * 1024 + 512;

    float4 q0, q1, q2, q3;                         // in-flight A regs (next tile)
    auto loadA = [&]() {
        q0 = ((const float4*)gA)[0]; q1 = ((const float4*)gA)[1];
        q2 = ((const float4*)gA)[2]; q3 = ((const float4*)gA)[3];
        gA += 32;
    };
    auto stageB = [&](int buf) {
        gl_lds16(gbh0, &sm[buf][2][lo0]); gl_lds16(gbh1, &sm[buf][2][lo1]);
        gl_lds16(gbl0, &sm[buf][3][lo0]); gl_lds16(gbl1, &sm[buf][3][lo1]);
        gbh0 += 32; gbh1 += 32; gbl0 += 32; gbl1 += 32;
    };
    auto writeA = [&](int buf) {
        float vv[16] = {q0.x, q0.y, q0.z, q0.w, q1.x, q1.y, q1.z, q1.w,
                        q2.x, q2.y, q2.z, q2.w, q3.x, q3.y, q3.z, q3.w};
        union { ushort_t u[8]; short8 v; } h0u, h1u, l0u, l1u;
        #pragma unroll
        for (int j = 0; j < 8; ++j) {
            ushort_t h = f2bf(vv[j]);
            h0u.u[j] = h; l0u.u[j] = f2bf(vv[j] - bf2f(h));
        }
        #pragma unroll
        for (int j = 0; j < 8; ++j) {
            ushort_t h = f2bf(vv[8 + j]);
            h1u.u[j] = h; l1u.u[j] = f2bf(vv[8 + j] - bf2f(h));
        }
        *(short8*)&sm[buf][0][wo0] = h0u.v; *(short8*)&sm[buf][0][wo1] = h1u.v;
        *(short8*)&sm[buf][1][wo0] = l0u.v; *(short8*)&sm[buf][1][wo1] = l1u.v;
    };

    floatx4 zero = {0.f, 0.f, 0.f, 0.f};
    floatx4 acc[4][4];
    #pragma unroll
    for (int i = 0; i < 4; ++i)
        #pragma unroll
        for (int j = 0; j < 4; ++j) acc[i][j] = zero;

    const int wm = (wave & 1) * 64, wn = (wave >> 1) * 64;
    const int fr = lane & 15, fq = lane >> 4;
    const int sx = SWZ(fr);

    // prologue: stage tile 0, have A(1) in flight
    loadA();                                       // A(0)
    stageB(0);
    writeA(0);                                     // waits A(0) only
    loadA();                                       // A(1) in flight
    asm volatile("s_waitcnt vmcnt(4) lgkmcnt(0)" ::: "memory");   // B(0) done
    __builtin_amdgcn_sched_barrier(0);
    __builtin_amdgcn_s_barrier();
    __builtin_amdgcn_sched_barrier(0);

    #pragma unroll 2
    for (int t = 0; t < NT; ++t) {
        const int cur = t & 1, nxt = cur ^ 1;
        if (t + 1 < NT) stageB(nxt);               // issue B(t+1) first
        short8 afh[4], afl[4], bfh[4], bfl[4];
        #pragma unroll
        for (int tt = 0; tt < 4; ++tt) {
            int ai = (wm + tt * 16 + fr) * 32 + (fq * 8 ^ sx);
            int bi = (wn + tt * 16 + fr) * 32 + (fq * 8 ^ sx);
            afh[tt] = *(const short8*)&sm[cur][0][ai];
            afl[tt] = *(const short8*)&sm[cur][1][ai];
            bfh[tt] = *(const short8*)&sm[cur][2][bi];
            bfl[tt] = *(const short8*)&sm[cur][3][bi];
        }
        if (t + 1 < NT) {
            writeA(nxt);                           // convert A(t+1), ds_write
            __builtin_amdgcn_sched_barrier(0);     // pin: gl_lds before A-loads
            if (t + 2 < NT) loadA();               // A(t+2) stays in flight
        }
        #pragma unroll
        for (int i = 0; i < 4; ++i)
            #pragma unroll
            for (int j = 0; j < 4; ++j) {
                acc[i][j] = __builtin_amdgcn_mfma_f32_16x16x32_bf16(afh[i], bfh[j], acc[i][j], 0, 0, 0);
                acc[i][j] = __builtin_amdgcn_mfma_f32_16x16x32_bf16(afh[i], bfl[j], acc[i][j], 0, 0, 0);
                acc[i][j] = __builtin_amdgcn_mfma_f32_16x16x32_bf16(afl[i], bfh[j], acc[i][j], 0, 0, 0);
            }
        if (t + 1 < NT) {
            if (t + 2 < NT) SYNC_PIPE(4);          // B(t+1) done, A(t+2) in flight
            else            SYNC_PIPE(0);          // tail: nothing to keep in flight
        }
    }
    const int colb = n0 + wn + fr;
    #pragma unroll
    for (int i = 0; i < 4; ++i) {
        int rowb = m0 + wm + i * 16 + fq * 4;
        #pragma unroll
        for (int r = 0; r < 4; ++r) {
            int row = rowb + r;
            if (row < M) {
                float dv = dinv[row];              // pre-scale for aggregation
                _Float16* cp = C + (size_t)row * N + colb;
                cp[0]  = (_Float16)(acc[i][0][r] * dv);
                cp[16] = (_Float16)(acc[i][1][r] * dv);
                cp[32] = (_Float16)(acc[i][2][r] * dv);
                cp[48] = (_Float16)(acc[i][3][r] * dv);
            }
        }
    }
}

// =====================================================================
// GEMM (split-bf16 A/B, all global_load_lds), double-buffered pipeline.
// Epilogue pre-scales rows by dinv[row] (consumed by aggregation).
// =====================================================================
template <int KT>
__global__ __launch_bounds__(256, 2) void gemm_bf(const ushort_t* __restrict__ Ah,
                                                  const ushort_t* __restrict__ Al,
                                                  const ushort_t* __restrict__ BhT,
                                                  const ushort_t* __restrict__ BlT,
                                                  const float* __restrict__ dinv,
                                                  _Float16* __restrict__ C,
                                                  int M, int N) {
    constexpr int NT = KT / 32;
    __shared__ ushort_t sm[2][4][128 * 32];
    const int tid  = threadIdx.x;
    const int wave = tid >> 6, lane = tid & 63;
    const int m0 = blockIdx.y * 128, n0 = blockIdx.x * 128;

    const int c0 = wave * 128 + lane, c1 = c0 + 64;
    const int ar0 = min(m0 + (c0 >> 2), M - 1), ar1 = min(m0 + (c1 >> 2), M - 1);
    const ushort_t* gah0 = Ah + (size_t)ar0 * KT + (c0 & 3) * 8;
    const ushort_t* gah1 = Ah + (size_t)ar1 * KT + (c1 & 3) * 8;
    const ushort_t* gal0 = Al + (size_t)ar0 * KT + (c0 & 3) * 8;
    const ushort_t* gal1 = Al + (size_t)ar1 * KT + (c1 & 3) * 8;
    const ushort_t* gbh0 = BhT + (size_t)(n0 + (c0 >> 2)) * KT + (c0 & 3) * 8;
    const ushort_t* gbh1 = BhT + (size_t)(n0 + (c1 >> 2)) * KT + (c1 & 3) * 8;
    const ushort_t* gbl0 = BlT + (size_t)(n0 + (c0 >> 2)) * KT + (c0 & 3) * 8;
    const ushort_t* gbl1 = BlT + (size_t)(n0 + (c1 >> 2)) * KT + (c1 & 3) * 8;
    const int lo0 = wave * 1024, lo1 = wave * 1024 + 512;

    auto stage = [&](int buf) {
        gl_lds16(gah0, &sm[buf][0][lo0]); gl_lds16(gah1, &sm[buf][0][lo1]);
        gl_lds16(gal0, &sm[buf][1][lo0]); gl_lds16(gal1, &sm[buf][1][lo1]);
        gl_lds16(gbh0, &sm[buf][2][lo0]); gl_lds16(gbh1, &sm[buf][2][lo1]);
        gl_lds16(gbl0, &sm[buf][3][lo0]); gl_lds16(gbl1, &sm[buf][3][lo1]);
        gah0 += 32; gah1 += 32; gal0 += 32; gal1 += 32;
        gbh0 += 32; gbh1 += 32; gbl0 += 32; gbl1 += 32;
    };

    floatx4 zero = {0.f, 0.f, 0.f, 0.f};
    floatx4 acc[4][4];
    #pragma unroll
    for (int i = 0; i < 4; ++i)
        #pragma unroll
        for (int j = 0; j < 4; ++j) acc[i][j] = zero;

    const int wm = (wave & 1) * 64, wn = (wave >> 1) * 64;
    const int fr = lane & 15, fq = lane >> 4;
    const int sx = SWZ(fr);

    stage(0);
    SYNC_PIPE(0);

    #pragma unroll 2
    for (int t = 0; t < NT; ++t) {
        const int cur = t & 1, nxt = cur ^ 1;
        if (t + 1 < NT) stage(nxt);                // issue next tile first
        short8 afh[4], afl[4], bfh[4], bfl[4];
        #pragma unroll
        for (int tt = 0; tt < 4; ++tt) {
            int ai = (wm + tt * 16 + fr) * 32 + (fq * 8 ^ sx);
            int bi = (wn + tt * 16 + fr) * 32 + (fq * 8 ^ sx);
            afh[tt] = *(const short8*)&sm[cur][0][ai];
            afl[tt] = *(const short8*)&sm[cur][1][ai];
            bfh[tt] = *(const short8*)&sm[cur][2][bi];
            bfl[tt] = *(const short8*)&sm[cur][3][bi];
        }
        #pragma unroll
        for (int i = 0; i < 4; ++i)
            #pragma unroll
            for (int j = 0; j < 4; ++j) {
                acc[i][j] = __builtin_amdgcn_mfma_f32_16x16x32_bf16(afh[i], bfh[j], acc[i][j], 0, 0, 0);
                acc[i][j] = __builtin_amdgcn_mfma_f32_16x16x32_bf16(afh[i], bfl[j], acc[i][j], 0, 0, 0);
                acc[i][j] = __builtin_amdgcn_mfma_f32_16x16x32_bf16(afl[i], bfh[j], acc[i][j], 0, 0, 0);
            }
        if (t + 1 < NT) SYNC_PIPE(0);
    }
    const int colb = n0 + wn + fr;
    #pragma unroll
    for (int i = 0; i < 4; ++i) {
        int rowb = m0 + wm + i * 16 + fq * 4;
        #pragma unroll
        for (int r = 0; r < 4; ++r) {
            int row = rowb + r;
            if (row < M) {
                float dv = dinv[row];
                _Float16* cp = C + (size_t)row * N + colb;
                cp[0]  = (_Float16)(acc[i][0][r] * dv);
                cp[16] = (_Float16)(acc[i][1][r] * dv);
                cp[32] = (_Float16)(acc[i][2][r] * dv);
                cp[48] = (_Float16)(acc[i][3][r] * dv);
            }
        }
    }
}

// =====================================================================
// PGE GEMM: p-tile = h1 @ PW, pipelined, with FUSED column max/argmax.
// =====================================================================
__global__ __launch_bounds__(256, 2) void gemm_pge(const ushort_t* __restrict__ Ah,
                                                   const ushort_t* __restrict__ Al,
                                                   const ushort_t* __restrict__ BhT,
                                                   const ushort_t* __restrict__ BlT,
                                                   float* __restrict__ pv,
                                                   int* __restrict__ pi,
                                                   int M) {
    constexpr int KT = OUT_CH;                     // 128
    constexpr int NT = KT / 32;                    // 4
    __shared__ ushort_t sm[2][4][128 * 32];
    __shared__ float redv[8][128];
    __shared__ int   redi[8][128];
    const int tid  = threadIdx.x;
    const int wave = tid >> 6, lane = tid & 63;
    const int m0 = blockIdx.x * 128;

    const int c0 = wave * 128 + lane, c1 = c0 + 64;
    const int ar0 = min(m0 + (c0 >> 2), M - 1), ar1 = min(m0 + (c1 >> 2), M - 1);
    const ushort_t* gah0 = Ah + (size_t)ar0 * KT + (c0 & 3) * 8;
    const ushort_t* gah1 = Ah + (size_t)ar1 * KT + (c1 & 3) * 8;
    const ushort_t* gal0 = Al + (size_t)ar0 * KT + (c0 & 3) * 8;
    const ushort_t* gal1 = Al + (size_t)ar1 * KT + (c1 & 3) * 8;
    const ushort_t* gbh0 = BhT + (size_t)(c0 >> 2) * KT + (c0 & 3) * 8;
    const ushort_t* gbh1 = BhT + (size_t)(c1 >> 2) * KT + (c1 & 3) * 8;
    const ushort_t* gbl0 = BlT + (size_t)(c0 >> 2) * KT + (c0 & 3) * 8;
    const ushort_t* gbl1 = BlT + (size_t)(c1 >> 2) * KT + (c1 & 3) * 8;
    const int lo0 = wave * 1024, lo1 = wave * 1024 + 512;

    auto stage = [&](int buf) {
        gl_lds16(gah0, &sm[buf][0][lo0]); gl_lds16(gah1, &sm[buf][0][lo1]);
        gl_lds16(gal0, &sm[buf][1][lo0]); gl_lds16(gal1, &sm[buf][1][lo1]);
        gl_lds16(gbh0, &sm[buf][2][lo0]); gl_lds16(gbh1, &sm[buf][2][lo1]);
        gl_lds16(gbl0, &sm[buf][3][lo0]); gl_lds16(gbl1, &sm[buf][3][lo1]);
        gah0 += 32; gah1 += 32; gal0 += 32; gal1 += 32;
        gbh0 += 32; gbh1 += 32; gbl0 += 32; gbl1 += 32;
    };

    floatx4 zero = {0.f, 0.f, 0.f, 0.f};
    floatx4 acc[4][4];
    #pragma unroll
    for (int i = 0; i < 4; ++i)
        #pragma unroll
        for (int j = 0; j < 4; ++j) acc[i][j] = zero;

    const int wm = (wave & 1) * 64, wn = (wave >> 1) * 64;
    const int fr = lane & 15, fq = lane >> 4;
    const int sx = SWZ(fr);

    stage(0);
    SYNC_PIPE(0);

    #pragma unroll 2
    for (int t = 0; t < NT; ++t) {
        const int cur = t & 1, nxt = cur ^ 1;
        if (t + 1 < NT) stage(nxt);
        short8 afh[4], afl[4], bfh[4], bfl[4];
        #pragma unroll
        for (int tt = 0; tt < 4; ++tt) {
            int ai = (wm + tt * 16 + fr) * 32 + (fq * 8 ^ sx);
            int bi = (wn + tt * 16 + fr) * 32 + (fq * 8 ^ sx);
            afh[tt] = *(const short8*)&sm[cur][0][ai];
            afl[tt] = *(const short8*)&sm[cur][1][ai];
            bfh[tt] = *(const short8*)&sm[cur][2][bi];
            bfl[tt] = *(const short8*)&sm[cur][3][bi];
        }
        #pragma unroll
        for (int i = 0; i < 4; ++i)
            #pragma unroll
            for (int j = 0; j < 4; ++j) {
                acc[i][j] = __builtin_amdgcn_mfma_f32_16x16x32_bf16(afh[i], bfh[j], acc[i][j], 0, 0, 0);
                acc[i][j] = __builtin_amdgcn_mfma_f32_16x16x32_bf16(afh[i], bfl[j], acc[i][j], 0, 0, 0);
                acc[i][j] = __builtin_amdgcn_mfma_f32_16x16x32_bf16(afl[i], bfh[j], acc[i][j], 0, 0, 0);
            }
        if (t + 1 < NT) SYNC_PIPE(0);
    }
    // ---- fused epilogue: column max/argmax over this 128-row strip ----
    __syncthreads();                               // safe reuse point (full drain)
    const int slot = (wave & 1) * 4 + fq;
    #pragma unroll
    for (int j = 0; j < 4; ++j) {
        float bv = -3.402823466e+38f; int bidx = 0;
        #pragma unroll
        for (int i = 0; i < 4; ++i) {
            int rowb = m0 + wm + i * 16 + fq * 4;
            #pragma unroll
            for (int r = 0; r < 4; ++r) {
                int row = rowb + r;
                float v = acc[i][j][r];
                if (row < M && v > bv) { bv = v; bidx = row; }   // strict > keeps lowest row
            }
        }
        redv[slot][wn + j * 16 + fr] = bv;
        redi[slot][wn + j * 16 + fr] = bidx;
    }
    __syncthreads();
    if (tid < 128) {
        float bv = redv[0][tid]; int bidx = redi[0][tid];
        #pragma unroll
        for (int s = 1; s < 8; ++s) {
            float v = redv[s][tid]; int ix = redi[s][tid];
            if (v > bv || (v == bv && ix < bidx)) { bv = v; bidx = ix; }
        }
        pv[blockIdx.x * 128 + tid] = bv;
        pi[blockIdx.x * 128 + tid] = bidx;
    }
}

// ---------------- aggregation (bucket gather, PRESCALED fp16 table) --------------------
// table row s = dinv[s]*hl[s]; out = di * (sum of rows) + bias.  Tail handled by one
// masked 8-wide batch (no serial dependent-load tail); summation order preserved.
__global__ __launch_bounds__(256) void agg256_relu_bf(const _Float16* __restrict__ hl,
                                                      const float* __restrict__ dinv,
                                                      const int* __restrict__ cnt,
                                                      const int* __restrict__ slots,
                                                      const float* __restrict__ bias,
                                                      ushort_t* __restrict__ oh,
                                                      ushort_t* __restrict__ ol) {
    int d = blockIdx.x * 4 + (threadIdx.x >> 6);
    int lane = threadIdx.x & 63;
    float di = dinv[d];
    half4v v = ((const half4v*)(hl + (size_t)d * 256))[lane];
    float ax = (float)v[0], ay = (float)v[1], az = (float)v[2], aw = (float)v[3];
    const int* sl = slots + (size_t)d * SLOT;
    int n = cnt[d];
    for (int e = 0; e < n; e += 8) {
        int s[8]; float m[8]; half4v u[8];
        #pragma unroll
        for (int j = 0; j < 8; ++j) {
            bool live = (e + j) < n;
            s[j] = live ? sl[e + j] : d;
            m[j] = live ? 1.0f : 0.0f;
        }
        #pragma unroll
        for (int j = 0; j < 8; ++j) u[j] = ((const half4v*)(hl + (size_t)s[j] * 256))[lane];
        #pragma unroll
        for (int j = 0; j < 8; ++j) {
            ax += m[j] * (float)u[j][0]; ay += m[j] * (float)u[j][1];
            az += m[j] * (float)u[j][2]; aw += m[j] * (float)u[j][3];
        }
    }
    float4 b = ((const float4*)bias)[lane];
    float rx = fmaxf(fmaf(di, ax, b.x), 0.0f), ry = fmaxf(fmaf(di, ay, b.y), 0.0f);
    float rz = fmaxf(fmaf(di, az, b.z), 0.0f), rw = fmaxf(fmaf(di, aw, b.w), 0.0f);
    ushort4 hv, lv;
    hv.x = f2bf(rx); lv.x = f2bf(rx - bf2f(hv.x));
    hv.y = f2bf(ry); lv.y = f2bf(ry - bf2f(hv.y));
    hv.z = f2bf(rz); lv.z = f2bf(rz - bf2f(hv.z));
    hv.w = f2bf(rw); lv.w = f2bf(rw - bf2f(hv.w));
    int sidx = (lane * 4) ^ SWZ(d);                // pre-swizzled split storage
    *(ushort4*)&oh[(size_t)d * 256 + sidx] = hv;
    *(ushort4*)&ol[(size_t)d * 256 + sidx] = lv;
}

__global__ __launch_bounds__(256) void agg128_bias_bf(const _Float16* __restrict__ hl,
                                                      const float* __restrict__ dinv,
                                                      const int* __restrict__ cnt,
                                                      const int* __restrict__ slots,
                                                      const float* __restrict__ bias,
                                                      float* __restrict__ out,
                                                      ushort_t* __restrict__ oh,
                                                      ushort_t* __restrict__ ol) {
    int d = blockIdx.x * 4 + (threadIdx.x >> 6);
    int lane = threadIdx.x & 63;
    float di = dinv[d];
    half2v v = ((const half2v*)(hl + (size_t)d * 128))[lane];
    float ax = (float)v[0], ay = (float)v[1];
    const int* sl = slots + (size_t)d * SLOT;
    int n = cnt[d];
    for (int e = 0; e < n; e += 8) {
        int s[8]; float m[8]; half2v u[8];
        #pragma unroll
        for (int j = 0; j < 8; ++j) {
            bool live = (e + j) < n;
            s[j] = live ? sl[e + j] : d;
            m[j] = live ? 1.0f : 0.0f;
        }
        #pragma unroll
        for (int j = 0; j < 8; ++j) u[j] = ((const half2v*)(hl + (size_t)s[j] * 128))[lane];
        #pragma unroll
        for (int j = 0; j < 8; ++j) { ax += m[j] * (float)u[j][0]; ay += m[j] * (float)u[j][1]; }
    }
    float2 b = ((const float2*)bias)[lane];
    float rx = fmaf(di, ax, b.x), ry = fmaf(di, ay, b.y);  // no relu (last conv layer)
    ((float2*)(out + (size_t)d * 128))[lane] = make_float2(rx, ry);
    ushort2 hv, lv;
    hv.x = f2bf(rx); lv.x = f2bf(rx - bf2f(hv.x));
    hv.y = f2bf(ry); lv.y = f2bf(ry - bf2f(hv.y));
    int sidx = (lane * 2) ^ SWZ(d);                // pre-swizzled split storage
    *(ushort2*)&oh[(size_t)d * 128 + sidx] = hv;
    *(ushort2*)&ol[(size_t)d * 128 + sidx] = lv;
}

// ---------------- final reduce over NB2 per-block partials ----------------
__global__ __launch_bounds__(256) void k_reduce2(const float* __restrict__ pv,
                                                 const int* __restrict__ pi,
                                                 const float* __restrict__ Pb,
                                                 float* __restrict__ out) {
    int c = threadIdx.x & 127, sub = threadIdx.x >> 7;
    float best = -3.402823466e+38f;
    int bi = 0;
    for (int b = sub; b < NB2; b += 2) {
        float v = pv[b * 128 + c];
        int ix = pi[b * 128 + c];
        if (v > best || (v == best && ix < bi)) { best = v; bi = ix; }
    }
    __shared__ float sv[128];
    __shared__ int   si[128];
    if (sub == 1) { sv[c] = best; si[c] = bi; }
    __syncthreads();
    if (sub == 0) {
        float v1 = sv[c]; int i1 = si[c];
        if (v1 > best || (v1 == best && i1 < bi)) { best = v1; bi = i1; }
        out[(size_t)N_NODES * OUT_CH + c]       = best + Pb[c];
        out[(size_t)N_NODES * OUT_CH + 128 + c] = (float)bi;
    }
}

extern "C" void kernel_launch(void* const* d_in, const int* in_sizes, int n_in,
                              void* d_out, int out_size, void* d_ws, size_t ws_size,
                              hipStream_t stream) {
    const float* x  = (const float*)d_in[0];
    const int*   ei = (const int*)d_in[1];
    const float* W0 = (const float*)d_in[2];
    const float* b0 = (const float*)d_in[3];
    const float* W1 = (const float*)d_in[4];
    const float* b1 = (const float*)d_in[5];
    const float* PW = (const float*)d_in[6];
    const float* Pb = (const float*)d_in[7];
    float* out = (float*)d_out;
    const int* esrc = ei;
    const int* edst = ei + N_EDGES;

    char* w = (char*)d_ws;
    size_t off = 0;
    auto alloc = [&](size_t bytes) -> void* {
        void* p = (void*)(w + off);
        off = (off + bytes + 255) & ~(size_t)255;
        return p;
    };
    int*       cnt    = (int*)alloc((size_t)N_NODES * 4);
    float*     dinv   = (float*)alloc((size_t)N_NODES * 4);
    int*       slots  = (int*)alloc((size_t)N_NODES * SLOT * 4);
    float*     pmax_v = (float*)alloc((size_t)NB2 * 128 * 4);
    int*       pmax_i = (int*)alloc((size_t)NB2 * 128 * 4);
    _Float16*  bufH   = (_Float16*)alloc((size_t)NPAD * 256 * 2);        // fp16 gather table
    ushort_t*  h0h    = (ushort_t*)alloc((size_t)N_NODES * HID_CH * 2);  // swizzled split
    ushort_t*  h0l    = (ushort_t*)alloc((size_t)N_NODES * HID_CH * 2);
    ushort_t*  h1h    = (ushort_t*)alloc((size_t)N_NODES * OUT_CH * 2);
    ushort_t*  h1l    = (ushort_t*)alloc((size_t)N_NODES * OUT_CH * 2);
    ushort_t*  W0hT   = (ushort_t*)alloc((size_t)IN_CH * HID_CH * 2);
    ushort_t*  W0lT   = (ushort_t*)alloc((size_t)IN_CH * HID_CH * 2);
    ushort_t*  W1hT   = (ushort_t*)alloc((size_t)HID_CH * OUT_CH * 2);
    ushort_t*  W1lT   = (ushort_t*)alloc((size_t)HID_CH * OUT_CH * 2);
    ushort_t*  PWhT   = (ushort_t*)alloc((size_t)OUT_CH * OUT_CH * 2);
    ushort_t*  PWlT   = (ushort_t*)alloc((size_t)OUT_CH * OUT_CH * 2);

    // --- prep: cnt zero + weight split/transpose (swizzled) ---
    k_prep<<<PPWB, 256, 0, stream>>>(W0, W1, PW, cnt,
                                     W0hT, W0lT, W1hT, W1lT, PWhT, PWlT);
    // --- padded-bucket CSR + dinv ---
    k_bucket<<<NB_E, 256, 0, stream>>>(esrc, edst, cnt, slots);
    k_dinv<<<196, 256, 0, stream>>>(cnt, dinv);

    // --- layer 0: table = dinv .* (x @ W0) ; h0 = relu(di*sum + b0) ---
    gemm0_x<<<dim3(HID_CH / 128, NB2), 256, 0, stream>>>(
        x, W0hT, W0lT, dinv, bufH, N_NODES, HID_CH);
    agg256_relu_bf<<<N_NODES / 4, 256, 0, stream>>>(bufH, dinv, cnt, slots, b0, h0h, h0l);

    // --- layer 1: table = dinv .* (h0 @ W1) ; h1 = di*sum + b1 -> d_out + split ---
    gemm_bf<HID_CH><<<dim3(1, NB2), 256, 0, stream>>>(
        h0h, h0l, W1hT, W1lT, dinv, bufH, N_NODES, OUT_CH);
    agg128_bias_bf<<<N_NODES / 4, 256, 0, stream>>>(bufH, dinv, cnt, slots, b1,
                                                    out, h1h, h1l);

    // --- PGE: fused p = h1 @ PW with per-block max/argmax; final reduce ---
    gemm_pge<<<NB2, 256, 0, stream>>>(h1h, h1l, PWhT, PWlT, pmax_v, pmax_i, N_NODES);
    k_reduce2<<<1, 256, 0, stream>>>(pmax_v, pmax_i, Pb, out);

    (void)in_sizes; (void)n_in; (void)out_size; (void)ws_size;
}